// Round 29
// baseline (138.349 us; speedup 1.0000x reference)
//
#include <hip/hip_runtime.h>
#include <hip/hip_bf16.h>
#include <math.h>

// out[b] = max_o( 2 * gelu_tanh( x[b,:] . weight[o,:] + bias[o] ) )
// 4096 x 4096 x 4096, fp32 in, fp32 out[4096].
//
// FINAL (= Round 23; best of 28 rounds, stable over 4 runs:
// 137.97 / 138.23 / 138.05 / 138.07 us total; ~108us GEMM, 1.27 PF,
// ~57% MfmaUtil, 0 bank conflicts, no spills).
// Structure:
//  - fp32->bf16 convert (one fused kernel, ~25us BW floor)
//  - 256x256x64 bf16 MFMA GEMM, 8 waves, 128 KiB dbuf LDS, 1 block/CU
//  - T1 XCD 2D swizzle; T2 XOR swizzle via pre-swizzled gload_lds source
//  - ONE barrier per K-tile; counted-lgkm wave drift (8/4/4/0 gates);
//    cross-boundary afP pre-read; NO setprio (R23 A/B, m190 regime)
//  - epilogue: row-max of (acc+bias); 2*gelu on the 4096 row-maxes only
// All catalog levers A/B'd (rounds 2-27); remaining candidates excluded
// by arithmetic (fp8 error budget, LDS capacity, convert fusion,
// cross-kernel overlap under graph capture).

typedef unsigned short u16;
typedef short bf16x8 __attribute__((ext_vector_type(8)));   // 8 bf16 = 4 VGPRs
typedef float f32x4 __attribute__((ext_vector_type(4)));
typedef unsigned short ushort8 __attribute__((ext_vector_type(8)));

#define MDIM 4096
#define NDIM 4096
#define KD   4096
#define BM 256
#define BN 256
#define BK 64
#define NKT (KD / BK)          // 64 K-tiles
#define NTN (NDIM / BN)        // 16 column tiles
#define HT  (128 * 64)         // u16 per half-tile (16 KB)

__device__ __forceinline__ u16 f2bf(float f) {
  unsigned int u = __float_as_uint(f);
  u += 0x7fffu + ((u >> 16) & 1u);
  return (u16)(u >> 16);
}

__global__ void f32_to_bf16_kernel(const float* __restrict__ in0,
                                   const float* __restrict__ in1,
                                   u16* __restrict__ out0,
                                   u16* __restrict__ out1, int n8) {
  int i = blockIdx.x * blockDim.x + threadIdx.x;
  int stride = gridDim.x * blockDim.x;
  for (; i < 2 * n8; i += stride) {
    const float* in = (i < n8) ? in0 : in1;
    u16* out = (i < n8) ? out0 : out1;
    int k = (i < n8) ? i : i - n8;
    const float4* p = (const float4*)in + (size_t)k * 2;
    float4 a = p[0];
    float4 b = p[1];
    ushort8 o;
    o[0] = f2bf(a.x); o[1] = f2bf(a.y); o[2] = f2bf(a.z); o[3] = f2bf(a.w);
    o[4] = f2bf(b.x); o[5] = f2bf(b.y); o[6] = f2bf(b.z); o[7] = f2bf(b.w);
    ((ushort8*)out)[k] = o;
  }
}

__device__ __forceinline__ void gload_lds16(const u16* g, u16* l) {
  __builtin_amdgcn_global_load_lds(
      (__attribute__((address_space(1))) void*)(g),
      (__attribute__((address_space(3))) void*)(l), 16, 0, 0);
}

#define LDSOFF(buf, arr, half) ((((((buf) * 2) + (arr)) * 2) + (half)) * HT)
#define SBAR0 __builtin_amdgcn_sched_barrier(0)

// Stage whole next K-tile into buffer `c` (8 gload_lds/thread), bump gp.
#define STAGE_TILE(c)                                                     \
  {                                                                       \
    _Pragma("unroll")                                                     \
    for (int q = 0; q < 8; ++q) {                                         \
      gload_lds16(gp[q], sm + LDSOFF((c), (q >> 2), ((q >> 1) & 1)) +     \
                             (q & 1) * 4096 + wdof);                      \
      gp[q] += BK;                                                        \
    }                                                                     \
  }

#define READ_A4(dst, c, ks, mg)                                           \
  {                                                                       \
    _Pragma("unroll")                                                     \
    for (int mm = 0; mm < 4; ++mm)                                        \
      dst[mm] = *(const bf16x8*)(ARB[(c)][(ks)] + ((mg)*4 + mm) * 1024);  \
  }

#define READ_B4(dst, c, ks)                                               \
  {                                                                       \
    _Pragma("unroll")                                                     \
    for (int n = 0; n < 4; ++n)                                           \
      dst[n] = *(const bf16x8*)(BRB[(c)][(ks)] + n * 1024);               \
  }

// 16 MFMA cluster (no setprio -- R23's proven win)
#define MFMA16(af, bfv, mg)                                               \
  {                                                                       \
    _Pragma("unroll")                                                     \
    for (int mm = 0; mm < 4; ++mm)                                        \
      _Pragma("unroll")                                                   \
      for (int n = 0; n < 4; ++n)                                         \
        acc[(mg)*4 + mm][n] = __builtin_amdgcn_mfma_f32_16x16x32_bf16(    \
            af[mm], bfv[n], acc[(mg)*4 + mm][n], 0, 0, 0);                \
  }

#define LGKM(n)                                                           \
  SBAR0;                                                                  \
  asm volatile("s_waitcnt lgkmcnt(" #n ")" ::: "memory");                 \
  SBAR0;

// One K-tile on buffer c. Entering: afP=A(c,ks0,mg0) issued at end of the
// PREVIOUS tile (4 outstanding).
//   issue bfP(c,ks0) [8], afQ(c,ks1,mg0) [12], bfQ(c,ks1) [16]; stage
//   lgkm(8)  -> c1(afP,bfP,mg0)       [first 8 landed]
//   rd afP <- A(c,ks0,mg1)            [<=12 out]
//   lgkm(4)  -> c2(afQ,bfQ,mg0)       [reads 9-16 landed]
//   rd afQ <- A(c,ks1,mg1)            [<=8 out]
//   lgkm(4)  -> c3(afP,bfP,mg1)
//   lgkm(0); vmcnt(0); s_barrier
//   rd afP <- A(c^1,ks0,mg0)          [next tile's first A operand]
//   c4(afQ,bfQ,mg1)                   [overlaps their service]
#define TILE(c, ST, LAST)                                                 \
  {                                                                       \
    READ_B4(bfP, c, 0)                                                    \
    SBAR0;                                                                \
    READ_A4(afQ, c, 1, 0)                                                 \
    SBAR0;                                                                \
    READ_B4(bfQ, c, 1)                                                    \
    SBAR0;                                                                \
    if (ST) { STAGE_TILE((c) ^ 1) }                                       \
    LGKM(8)                                                               \
    MFMA16(afP, bfP, 0)                                                   \
    SBAR0;                                                                \
    READ_A4(afP, c, 0, 1)                                                 \
    LGKM(4)                                                               \
    MFMA16(afQ, bfQ, 0)                                                   \
    SBAR0;                                                                \
    READ_A4(afQ, c, 1, 1)                                                 \
    LGKM(4)                                                               \
    MFMA16(afP, bfP, 1)                                                   \
    LGKM(0)                                                               \
    if (!LAST) {                                                          \
      asm volatile("s_waitcnt vmcnt(0)" ::: "memory");                    \
      __builtin_amdgcn_s_barrier();                                       \
      READ_A4(afP, (c) ^ 1, 0, 0)                                         \
      SBAR0;                                                              \
    }                                                                     \
    MFMA16(afQ, bfQ, 1)                                                   \
    SBAR0;                                                                \
  }

__global__ __launch_bounds__(512, 2) void gemm_gelu_max_kernel(
    const u16* __restrict__ A,    // x bf16 [4096][4096], K contiguous
    const u16* __restrict__ Bw,   // weight bf16 [4096][4096], K contiguous
    const float* __restrict__ bias,
    float* __restrict__ partials) {
  __shared__ __align__(16) u16 sm[2 * 2 * 2 * HT];  // 128 KiB
  __shared__ float pmx[8][128];                      // 4 KiB

  const int t = threadIdx.x;
  const int wave = t >> 6;
  const int lane = t & 63;
  const int warp_m = wave >> 2;        // A half
  const int warp_n = wave & 3;
  const int wn2 = warp_n >> 1;         // B half
  const int bn0 = (warp_n & 1) * 64;   // col base within B half
  const int l15 = lane & 15;
  const int l4 = lane >> 4;
  const int l7 = lane & 7;
  const int wdof = wave * 512;         // wave's gload_lds dest slot (u16)

  // T1: XCD-aware 2D swizzle (bid%8 -> XCD; XCD owns 4x8 tile region)
  const int bid = blockIdx.x;
  const int c8 = bid & 7;
  const int j = bid >> 3;
  const int tx = ((c8 & 3) << 2) + (j & 3);    // 0..15
  const int ty = ((c8 >> 2) << 3) + (j >> 2);  // 0..15
  const int brow = ty * BM;
  const int bcol = tx * BN;

  // per-thread swizzled 16B-chunk offsets (u16 elems) for k-slice 0/1
  const int cko0 = ((l4 ^ l7) << 3);
  const int cko1 = (((4 + l4) ^ l7) << 3);

  // LDS read base pointers per (buffer, ks); frag offsets are const imm
  const u16* ARB[2][2];
  const u16* BRB[2][2];
#pragma unroll
  for (int c = 0; c < 2; ++c) {
    ARB[c][0] = sm + LDSOFF(c, 0, warp_m) + l15 * 64 + cko0;
    ARB[c][1] = sm + LDSOFF(c, 0, warp_m) + l15 * 64 + cko1;
    BRB[c][0] = sm + LDSOFF(c, 1, wn2) + bn0 * 64 + l15 * 64 + cko0;
    BRB[c][1] = sm + LDSOFF(c, 1, wn2) + bn0 * 64 + l15 * 64 + cko1;
  }

  // running global staging pointers (pre-swizzled source, rule #21)
  const u16* gp[8];
#pragma unroll
  for (int it = 0; it < 2; ++it) {
    const int chunk = it * 512 + t;
    const int r = chunk >> 3;
    const int sw = ((chunk & 7) ^ (r & 7)) << 3;
    gp[0 + it] = A  + (size_t)(brow + r) * KD + sw;        // A half0
    gp[2 + it] = A  + (size_t)(brow + 128 + r) * KD + sw;  // A half1
    gp[4 + it] = Bw + (size_t)(bcol + r) * KD + sw;        // B half0
    gp[6 + it] = Bw + (size_t)(bcol + 128 + r) * KD + sw;  // B half1
  }

  f32x4 acc[8][4] = {};   // per-wave 128x64 output (AGPR)
  bf16x8 afP[4], afQ[4], bfP[4], bfQ[4];

  // prologue: tile 0 -> buf 0; pre-read c1's A operand
  STAGE_TILE(0)
  asm volatile("s_waitcnt vmcnt(0)" ::: "memory");
  __builtin_amdgcn_s_barrier();
  READ_A4(afP, 0, 0, 0)
  SBAR0;

  for (int kt2 = 0; kt2 < NKT / 2 - 1; ++kt2) {   // tiles 0..61
    TILE(0, 1, 0)
    TILE(1, 1, 0)
  }
  TILE(0, 1, 0)    // tile 62 (stages tile 63 into buf1)
  TILE(1, 0, 1)    // tile 63

  // ---- epilogue: row-max of (acc + bias); gelu deferred to rowmax.
  // C/D layout per 16x16 frag: col = l15, row = l4*4 + j
  float rmax_[8][4];
#pragma unroll
  for (int m = 0; m < 8; ++m)
#pragma unroll
    for (int j2 = 0; j2 < 4; ++j2) rmax_[m][j2] = -1e30f;

#pragma unroll
  for (int n = 0; n < 4; ++n) {
    const float bv = bias[bcol + warp_n * 64 + n * 16 + l15];
#pragma unroll
    for (int m = 0; m < 8; ++m) {
#pragma unroll
      for (int j2 = 0; j2 < 4; ++j2)
        rmax_[m][j2] = fmaxf(rmax_[m][j2], acc[m][n][j2] + bv);
    }
  }

#pragma unroll
  for (int m = 0; m < 8; ++m) {
#pragma unroll
    for (int j2 = 0; j2 < 4; ++j2) {
      float v = rmax_[m][j2];
      v = fmaxf(v, __shfl_xor(v, 1, 64));
      v = fmaxf(v, __shfl_xor(v, 2, 64));
      v = fmaxf(v, __shfl_xor(v, 4, 64));
      v = fmaxf(v, __shfl_xor(v, 8, 64));
      if (l15 == 0) pmx[wave][m * 16 + l4 * 4 + j2] = v;
    }
  }
  __syncthreads();

  if (t < 256) {
    int gm = t >> 7;
    int r = t & 127;
    float v = fmaxf(fmaxf(pmx[gm * 4 + 0][r], pmx[gm * 4 + 1][r]),
                    fmaxf(pmx[gm * 4 + 2][r], pmx[gm * 4 + 3][r]));
    partials[(size_t)tx * MDIM + brow + t] = v;
  }
}

__global__ void rowmax_kernel(const float* __restrict__ partials,
                              float* __restrict__ out) {
  int r = blockIdx.x * blockDim.x + threadIdx.x;
  if (r < MDIM) {
    float m = -1e30f;
#pragma unroll
    for (int tt = 0; tt < NTN; ++tt) m = fmaxf(m, partials[(size_t)tt * MDIM + r]);
    // 2*gelu_tanh(m); valid since row-max >= 0 and gelu is increasing there
    float u = 0.7978845608f * m * (1.0f + 0.044715f * m * m);
    float e = exp2f(u * 2.8853900817779268f);   // 2*log2(e)
    float rc = __builtin_amdgcn_rcpf(e + 1.0f);
    out[r] = 2.0f * m * (1.0f - rc);
  }
}

extern "C" void kernel_launch(void* const* d_in, const int* in_sizes, int n_in,
                              void* d_out, int out_size, void* d_ws, size_t ws_size,
                              hipStream_t stream) {
  const float* x = (const float*)d_in[0];
  const float* w = (const float*)d_in[1];
  const float* bias = (const float*)d_in[2];
  float* out = (float*)d_out;

  u16* xb = (u16*)d_ws;
  u16* wb = xb + (size_t)MDIM * KD;
  float* partials = (float*)(wb + (size_t)NDIM * KD);

  const int n8 = (MDIM * KD) / 8;
  f32_to_bf16_kernel<<<2048, 256, 0, stream>>>(x, w, xb, wb, n8);

  gemm_gelu_max_kernel<<<dim3(256), 512, 0, stream>>>(xb, wb, bias, partials);

  rowmax_kernel<<<MDIM / 256, 256, 0, stream>>>(partials, out);
}

// Round 30
// 138.075 us; speedup vs baseline: 1.0020x; 1.0020x over previous
//
#include <hip/hip_runtime.h>
#include <hip/hip_bf16.h>
#include <math.h>

// out[b] = max_o( 2 * gelu_tanh( x[b,:] . weight[o,:] + bias[o] ) )
// 4096 x 4096 x 4096, fp32 in, fp32 out[4096].
//
// FINAL (= Round 23; best of 29 rounds, stable over 5 runs:
// 137.97 / 138.23 / 138.05 / 138.07 / 138.35 us total; ~107.5us GEMM,
// 1.27 PF, ~57% MfmaUtil, 0 bank conflicts, no spills).
// Structure:
//  - fp32->bf16 convert (one fused kernel, ~25us BW floor)
//  - 256x256x64 bf16 MFMA GEMM, 8 waves, 128 KiB dbuf LDS, 1 block/CU
//  - T1 XCD 2D swizzle; T2 XOR swizzle via pre-swizzled gload_lds source
//  - ONE barrier per K-tile; counted-lgkm wave drift (8/4/4/0 gates);
//    cross-boundary afP pre-read; NO setprio (R23 A/B, m190 regime)
//  - epilogue: row-max of (acc+bias); 2*gelu on the 4096 row-maxes only
// All catalog levers A/B'd (rounds 2-27); remaining candidates excluded
// by arithmetic (fp8 error budget, LDS capacity, convert fusion).

typedef unsigned short u16;
typedef short bf16x8 __attribute__((ext_vector_type(8)));   // 8 bf16 = 4 VGPRs
typedef float f32x4 __attribute__((ext_vector_type(4)));
typedef unsigned short ushort8 __attribute__((ext_vector_type(8)));

#define MDIM 4096
#define NDIM 4096
#define KD   4096
#define BM 256
#define BN 256
#define BK 64
#define NKT (KD / BK)          // 64 K-tiles
#define NTN (NDIM / BN)        // 16 column tiles
#define HT  (128 * 64)         // u16 per half-tile (16 KB)

__device__ __forceinline__ u16 f2bf(float f) {
  unsigned int u = __float_as_uint(f);
  u += 0x7fffu + ((u >> 16) & 1u);
  return (u16)(u >> 16);
}

__global__ void f32_to_bf16_kernel(const float* __restrict__ in0,
                                   const float* __restrict__ in1,
                                   u16* __restrict__ out0,
                                   u16* __restrict__ out1, int n8) {
  int i = blockIdx.x * blockDim.x + threadIdx.x;
  int stride = gridDim.x * blockDim.x;
  for (; i < 2 * n8; i += stride) {
    const float* in = (i < n8) ? in0 : in1;
    u16* out = (i < n8) ? out0 : out1;
    int k = (i < n8) ? i : i - n8;
    const float4* p = (const float4*)in + (size_t)k * 2;
    float4 a = p[0];
    float4 b = p[1];
    ushort8 o;
    o[0] = f2bf(a.x); o[1] = f2bf(a.y); o[2] = f2bf(a.z); o[3] = f2bf(a.w);
    o[4] = f2bf(b.x); o[5] = f2bf(b.y); o[6] = f2bf(b.z); o[7] = f2bf(b.w);
    ((ushort8*)out)[k] = o;
  }
}

__device__ __forceinline__ void gload_lds16(const u16* g, u16* l) {
  __builtin_amdgcn_global_load_lds(
      (__attribute__((address_space(1))) void*)(g),
      (__attribute__((address_space(3))) void*)(l), 16, 0, 0);
}

#define LDSOFF(buf, arr, half) ((((((buf) * 2) + (arr)) * 2) + (half)) * HT)
#define SBAR0 __builtin_amdgcn_sched_barrier(0)

// Stage whole next K-tile into buffer `c` (8 gload_lds/thread), bump gp.
#define STAGE_TILE(c)                                                     \
  {                                                                       \
    _Pragma("unroll")                                                     \
    for (int q = 0; q < 8; ++q) {                                         \
      gload_lds16(gp[q], sm + LDSOFF((c), (q >> 2), ((q >> 1) & 1)) +     \
                             (q & 1) * 4096 + wdof);                      \
      gp[q] += BK;                                                        \
    }                                                                     \
  }

#define READ_A4(dst, c, ks, mg)                                           \
  {                                                                       \
    _Pragma("unroll")                                                     \
    for (int mm = 0; mm < 4; ++mm)                                        \
      dst[mm] = *(const bf16x8*)(ARB[(c)][(ks)] + ((mg)*4 + mm) * 1024);  \
  }

#define READ_B4(dst, c, ks)                                               \
  {                                                                       \
    _Pragma("unroll")                                                     \
    for (int n = 0; n < 4; ++n)                                           \
      dst[n] = *(const bf16x8*)(BRB[(c)][(ks)] + n * 1024);               \
  }

// 16 MFMA cluster (no setprio -- R23's proven win)
#define MFMA16(af, bfv, mg)                                               \
  {                                                                       \
    _Pragma("unroll")                                                     \
    for (int mm = 0; mm < 4; ++mm)                                        \
      _Pragma("unroll")                                                   \
      for (int n = 0; n < 4; ++n)                                         \
        acc[(mg)*4 + mm][n] = __builtin_amdgcn_mfma_f32_16x16x32_bf16(    \
            af[mm], bfv[n], acc[(mg)*4 + mm][n], 0, 0, 0);                \
  }

#define LGKM(n)                                                           \
  SBAR0;                                                                  \
  asm volatile("s_waitcnt lgkmcnt(" #n ")" ::: "memory");                 \
  SBAR0;

// One K-tile on buffer c. Entering: afP=A(c,ks0,mg0) issued at end of the
// PREVIOUS tile (4 outstanding).
//   issue bfP(c,ks0) [8], afQ(c,ks1,mg0) [12], bfQ(c,ks1) [16]; stage
//   lgkm(8)  -> c1(afP,bfP,mg0)       [first 8 landed]
//   rd afP <- A(c,ks0,mg1)            [<=12 out]
//   lgkm(4)  -> c2(afQ,bfQ,mg0)       [reads 9-16 landed]
//   rd afQ <- A(c,ks1,mg1)            [<=8 out]
//   lgkm(4)  -> c3(afP,bfP,mg1)
//   lgkm(0); vmcnt(0); s_barrier
//   rd afP <- A(c^1,ks0,mg0)          [next tile's first A operand]
//   c4(afQ,bfQ,mg1)                   [overlaps their service]
#define TILE(c, ST, LAST)                                                 \
  {                                                                       \
    READ_B4(bfP, c, 0)                                                    \
    SBAR0;                                                                \
    READ_A4(afQ, c, 1, 0)                                                 \
    SBAR0;                                                                \
    READ_B4(bfQ, c, 1)                                                    \
    SBAR0;                                                                \
    if (ST) { STAGE_TILE((c) ^ 1) }                                       \
    LGKM(8)                                                               \
    MFMA16(afP, bfP, 0)                                                   \
    SBAR0;                                                                \
    READ_A4(afP, c, 0, 1)                                                 \
    LGKM(4)                                                               \
    MFMA16(afQ, bfQ, 0)                                                   \
    SBAR0;                                                                \
    READ_A4(afQ, c, 1, 1)                                                 \
    LGKM(4)                                                               \
    MFMA16(afP, bfP, 1)                                                   \
    LGKM(0)                                                               \
    if (!LAST) {                                                          \
      asm volatile("s_waitcnt vmcnt(0)" ::: "memory");                    \
      __builtin_amdgcn_s_barrier();                                       \
      READ_A4(afP, (c) ^ 1, 0, 0)                                         \
      SBAR0;                                                              \
    }                                                                     \
    MFMA16(afQ, bfQ, 1)                                                   \
    SBAR0;                                                                \
  }

__global__ __launch_bounds__(512, 2) void gemm_gelu_max_kernel(
    const u16* __restrict__ A,    // x bf16 [4096][4096], K contiguous
    const u16* __restrict__ Bw,   // weight bf16 [4096][4096], K contiguous
    const float* __restrict__ bias,
    float* __restrict__ partials) {
  __shared__ __align__(16) u16 sm[2 * 2 * 2 * HT];  // 128 KiB
  __shared__ float pmx[8][128];                      // 4 KiB

  const int t = threadIdx.x;
  const int wave = t >> 6;
  const int lane = t & 63;
  const int warp_m = wave >> 2;        // A half
  const int warp_n = wave & 3;
  const int wn2 = warp_n >> 1;         // B half
  const int bn0 = (warp_n & 1) * 64;   // col base within B half
  const int l15 = lane & 15;
  const int l4 = lane >> 4;
  const int l7 = lane & 7;
  const int wdof = wave * 512;         // wave's gload_lds dest slot (u16)

  // T1: XCD-aware 2D swizzle (bid%8 -> XCD; XCD owns 4x8 tile region)
  const int bid = blockIdx.x;
  const int c8 = bid & 7;
  const int j = bid >> 3;
  const int tx = ((c8 & 3) << 2) + (j & 3);    // 0..15
  const int ty = ((c8 >> 2) << 3) + (j >> 2);  // 0..15
  const int brow = ty * BM;
  const int bcol = tx * BN;

  // per-thread swizzled 16B-chunk offsets (u16 elems) for k-slice 0/1
  const int cko0 = ((l4 ^ l7) << 3);
  const int cko1 = (((4 + l4) ^ l7) << 3);

  // LDS read base pointers per (buffer, ks); frag offsets are const imm
  const u16* ARB[2][2];
  const u16* BRB[2][2];
#pragma unroll
  for (int c = 0; c < 2; ++c) {
    ARB[c][0] = sm + LDSOFF(c, 0, warp_m) + l15 * 64 + cko0;
    ARB[c][1] = sm + LDSOFF(c, 0, warp_m) + l15 * 64 + cko1;
    BRB[c][0] = sm + LDSOFF(c, 1, wn2) + bn0 * 64 + l15 * 64 + cko0;
    BRB[c][1] = sm + LDSOFF(c, 1, wn2) + bn0 * 64 + l15 * 64 + cko1;
  }

  // running global staging pointers (pre-swizzled source, rule #21)
  const u16* gp[8];
#pragma unroll
  for (int it = 0; it < 2; ++it) {
    const int chunk = it * 512 + t;
    const int r = chunk >> 3;
    const int sw = ((chunk & 7) ^ (r & 7)) << 3;
    gp[0 + it] = A  + (size_t)(brow + r) * KD + sw;        // A half0
    gp[2 + it] = A  + (size_t)(brow + 128 + r) * KD + sw;  // A half1
    gp[4 + it] = Bw + (size_t)(bcol + r) * KD + sw;        // B half0
    gp[6 + it] = Bw + (size_t)(bcol + 128 + r) * KD + sw;  // B half1
  }

  f32x4 acc[8][4] = {};   // per-wave 128x64 output (AGPR)
  bf16x8 afP[4], afQ[4], bfP[4], bfQ[4];

  // prologue: tile 0 -> buf 0; pre-read c1's A operand
  STAGE_TILE(0)
  asm volatile("s_waitcnt vmcnt(0)" ::: "memory");
  __builtin_amdgcn_s_barrier();
  READ_A4(afP, 0, 0, 0)
  SBAR0;

  for (int kt2 = 0; kt2 < NKT / 2 - 1; ++kt2) {   // tiles 0..61
    TILE(0, 1, 0)
    TILE(1, 1, 0)
  }
  TILE(0, 1, 0)    // tile 62 (stages tile 63 into buf1)
  TILE(1, 0, 1)    // tile 63

  // ---- epilogue: row-max of (acc + bias); gelu deferred to rowmax.
  // C/D layout per 16x16 frag: col = l15, row = l4*4 + j
  float rmax_[8][4];
#pragma unroll
  for (int m = 0; m < 8; ++m)
#pragma unroll
    for (int j2 = 0; j2 < 4; ++j2) rmax_[m][j2] = -1e30f;

#pragma unroll
  for (int n = 0; n < 4; ++n) {
    const float bv = bias[bcol + warp_n * 64 + n * 16 + l15];
#pragma unroll
    for (int m = 0; m < 8; ++m) {
#pragma unroll
      for (int j2 = 0; j2 < 4; ++j2)
        rmax_[m][j2] = fmaxf(rmax_[m][j2], acc[m][n][j2] + bv);
    }
  }

#pragma unroll
  for (int m = 0; m < 8; ++m) {
#pragma unroll
    for (int j2 = 0; j2 < 4; ++j2) {
      float v = rmax_[m][j2];
      v = fmaxf(v, __shfl_xor(v, 1, 64));
      v = fmaxf(v, __shfl_xor(v, 2, 64));
      v = fmaxf(v, __shfl_xor(v, 4, 64));
      v = fmaxf(v, __shfl_xor(v, 8, 64));
      if (l15 == 0) pmx[wave][m * 16 + l4 * 4 + j2] = v;
    }
  }
  __syncthreads();

  if (t < 256) {
    int gm = t >> 7;
    int r = t & 127;
    float v = fmaxf(fmaxf(pmx[gm * 4 + 0][r], pmx[gm * 4 + 1][r]),
                    fmaxf(pmx[gm * 4 + 2][r], pmx[gm * 4 + 3][r]));
    partials[(size_t)tx * MDIM + brow + t] = v;
  }
}

__global__ void rowmax_kernel(const float* __restrict__ partials,
                              float* __restrict__ out) {
  int r = blockIdx.x * blockDim.x + threadIdx.x;
  if (r < MDIM) {
    float m = -1e30f;
#pragma unroll
    for (int tt = 0; tt < NTN; ++tt) m = fmaxf(m, partials[(size_t)tt * MDIM + r]);
    // 2*gelu_tanh(m); valid since row-max >= 0 and gelu is increasing there
    float u = 0.7978845608f * m * (1.0f + 0.044715f * m * m);
    float e = exp2f(u * 2.8853900817779268f);   // 2*log2(e)
    float rc = __builtin_amdgcn_rcpf(e + 1.0f);
    out[r] = 2.0f * m * (1.0f - rc);
  }
}

extern "C" void kernel_launch(void* const* d_in, const int* in_sizes, int n_in,
                              void* d_out, int out_size, void* d_ws, size_t ws_size,
                              hipStream_t stream) {
  const float* x = (const float*)d_in[0];
  const float* w = (const float*)d_in[1];
  const float* bias = (const float*)d_in[2];
  float* out = (float*)d_out;

  u16* xb = (u16*)d_ws;
  u16* wb = xb + (size_t)MDIM * KD;
  float* partials = (float*)(wb + (size_t)NDIM * KD);

  const int n8 = (MDIM * KD) / 8;
  f32_to_bf16_kernel<<<2048, 256, 0, stream>>>(x, w, xb, wb, n8);

  gemm_gelu_max_kernel<<<dim3(256), 512, 0, stream>>>(xb, wb, bias, partials);

  rowmax_kernel<<<MDIM / 256, 256, 0, stream>>>(partials, out);
}

// Round 31
// 137.731 us; speedup vs baseline: 1.0045x; 1.0025x over previous
//
#include <hip/hip_runtime.h>
#include <hip/hip_bf16.h>
#include <math.h>

// out[b] = max_o( 2 * gelu_tanh( x[b,:] . weight[o,:] + bias[o] ) )
// 4096 x 4096 x 4096, fp32 in, fp32 out[4096].
//
// FINAL (= Round 23; best of 30 rounds, stable over 6 runs:
// 137.97 / 138.23 / 138.05 / 138.07 / 138.35 / 138.08 us total;
// ~107.5us GEMM, 1.27 PF, ~57% MfmaUtil, 0 bank conflicts, no spills).
// Structure:
//  - fp32->bf16 convert (one fused kernel, ~25us BW floor)
//  - 256x256x64 bf16 MFMA GEMM, 8 waves, 128 KiB dbuf LDS, 1 block/CU
//  - T1 XCD 2D swizzle; T2 XOR swizzle via pre-swizzled gload_lds source
//  - ONE barrier per K-tile; counted-lgkm wave drift (8/4/4/0 gates);
//    cross-boundary afP pre-read; NO setprio (R23 A/B, m190 regime)
//  - epilogue: row-max of (acc+bias); 2*gelu on the 4096 row-maxes only
// All catalog levers A/B'd (rounds 2-27); remaining candidates excluded
// by arithmetic (fp8 error budget, LDS capacity, convert fusion).

typedef unsigned short u16;
typedef short bf16x8 __attribute__((ext_vector_type(8)));   // 8 bf16 = 4 VGPRs
typedef float f32x4 __attribute__((ext_vector_type(4)));
typedef unsigned short ushort8 __attribute__((ext_vector_type(8)));

#define MDIM 4096
#define NDIM 4096
#define KD   4096
#define BM 256
#define BN 256
#define BK 64
#define NKT (KD / BK)          // 64 K-tiles
#define NTN (NDIM / BN)        // 16 column tiles
#define HT  (128 * 64)         // u16 per half-tile (16 KB)

__device__ __forceinline__ u16 f2bf(float f) {
  unsigned int u = __float_as_uint(f);
  u += 0x7fffu + ((u >> 16) & 1u);
  return (u16)(u >> 16);
}

__global__ void f32_to_bf16_kernel(const float* __restrict__ in0,
                                   const float* __restrict__ in1,
                                   u16* __restrict__ out0,
                                   u16* __restrict__ out1, int n8) {
  int i = blockIdx.x * blockDim.x + threadIdx.x;
  int stride = gridDim.x * blockDim.x;
  for (; i < 2 * n8; i += stride) {
    const float* in = (i < n8) ? in0 : in1;
    u16* out = (i < n8) ? out0 : out1;
    int k = (i < n8) ? i : i - n8;
    const float4* p = (const float4*)in + (size_t)k * 2;
    float4 a = p[0];
    float4 b = p[1];
    ushort8 o;
    o[0] = f2bf(a.x); o[1] = f2bf(a.y); o[2] = f2bf(a.z); o[3] = f2bf(a.w);
    o[4] = f2bf(b.x); o[5] = f2bf(b.y); o[6] = f2bf(b.z); o[7] = f2bf(b.w);
    ((ushort8*)out)[k] = o;
  }
}

__device__ __forceinline__ void gload_lds16(const u16* g, u16* l) {
  __builtin_amdgcn_global_load_lds(
      (__attribute__((address_space(1))) void*)(g),
      (__attribute__((address_space(3))) void*)(l), 16, 0, 0);
}

#define LDSOFF(buf, arr, half) ((((((buf) * 2) + (arr)) * 2) + (half)) * HT)
#define SBAR0 __builtin_amdgcn_sched_barrier(0)

// Stage whole next K-tile into buffer `c` (8 gload_lds/thread), bump gp.
#define STAGE_TILE(c)                                                     \
  {                                                                       \
    _Pragma("unroll")                                                     \
    for (int q = 0; q < 8; ++q) {                                         \
      gload_lds16(gp[q], sm + LDSOFF((c), (q >> 2), ((q >> 1) & 1)) +     \
                             (q & 1) * 4096 + wdof);                      \
      gp[q] += BK;                                                        \
    }                                                                     \
  }

#define READ_A4(dst, c, ks, mg)                                           \
  {                                                                       \
    _Pragma("unroll")                                                     \
    for (int mm = 0; mm < 4; ++mm)                                        \
      dst[mm] = *(const bf16x8*)(ARB[(c)][(ks)] + ((mg)*4 + mm) * 1024);  \
  }

#define READ_B4(dst, c, ks)                                               \
  {                                                                       \
    _Pragma("unroll")                                                     \
    for (int n = 0; n < 4; ++n)                                           \
      dst[n] = *(const bf16x8*)(BRB[(c)][(ks)] + n * 1024);               \
  }

// 16 MFMA cluster (no setprio -- R23's proven win)
#define MFMA16(af, bfv, mg)                                               \
  {                                                                       \
    _Pragma("unroll")                                                     \
    for (int mm = 0; mm < 4; ++mm)                                        \
      _Pragma("unroll")                                                   \
      for (int n = 0; n < 4; ++n)                                         \
        acc[(mg)*4 + mm][n] = __builtin_amdgcn_mfma_f32_16x16x32_bf16(    \
            af[mm], bfv[n], acc[(mg)*4 + mm][n], 0, 0, 0);                \
  }

#define LGKM(n)                                                           \
  SBAR0;                                                                  \
  asm volatile("s_waitcnt lgkmcnt(" #n ")" ::: "memory");                 \
  SBAR0;

// One K-tile on buffer c. Entering: afP=A(c,ks0,mg0) issued at end of the
// PREVIOUS tile (4 outstanding).
//   issue bfP(c,ks0) [8], afQ(c,ks1,mg0) [12], bfQ(c,ks1) [16]; stage
//   lgkm(8)  -> c1(afP,bfP,mg0)       [first 8 landed]
//   rd afP <- A(c,ks0,mg1)            [<=12 out]
//   lgkm(4)  -> c2(afQ,bfQ,mg0)       [reads 9-16 landed]
//   rd afQ <- A(c,ks1,mg1)            [<=8 out]
//   lgkm(4)  -> c3(afP,bfP,mg1)
//   lgkm(0); vmcnt(0); s_barrier
//   rd afP <- A(c^1,ks0,mg0)          [next tile's first A operand]
//   c4(afQ,bfQ,mg1)                   [overlaps their service]
#define TILE(c, ST, LAST)                                                 \
  {                                                                       \
    READ_B4(bfP, c, 0)                                                    \
    SBAR0;                                                                \
    READ_A4(afQ, c, 1, 0)                                                 \
    SBAR0;                                                                \
    READ_B4(bfQ, c, 1)                                                    \
    SBAR0;                                                                \
    if (ST) { STAGE_TILE((c) ^ 1) }                                       \
    LGKM(8)                                                               \
    MFMA16(afP, bfP, 0)                                                   \
    SBAR0;                                                                \
    READ_A4(afP, c, 0, 1)                                                 \
    LGKM(4)                                                               \
    MFMA16(afQ, bfQ, 0)                                                   \
    SBAR0;                                                                \
    READ_A4(afQ, c, 1, 1)                                                 \
    LGKM(4)                                                               \
    MFMA16(afP, bfP, 1)                                                   \
    LGKM(0)                                                               \
    if (!LAST) {                                                          \
      asm volatile("s_waitcnt vmcnt(0)" ::: "memory");                    \
      __builtin_amdgcn_s_barrier();                                       \
      READ_A4(afP, (c) ^ 1, 0, 0)                                         \
      SBAR0;                                                              \
    }                                                                     \
    MFMA16(afQ, bfQ, 1)                                                   \
    SBAR0;                                                                \
  }

__global__ __launch_bounds__(512, 2) void gemm_gelu_max_kernel(
    const u16* __restrict__ A,    // x bf16 [4096][4096], K contiguous
    const u16* __restrict__ Bw,   // weight bf16 [4096][4096], K contiguous
    const float* __restrict__ bias,
    float* __restrict__ partials) {
  __shared__ __align__(16) u16 sm[2 * 2 * 2 * HT];  // 128 KiB
  __shared__ float pmx[8][128];                      // 4 KiB

  const int t = threadIdx.x;
  const int wave = t >> 6;
  const int lane = t & 63;
  const int warp_m = wave >> 2;        // A half
  const int warp_n = wave & 3;
  const int wn2 = warp_n >> 1;         // B half
  const int bn0 = (warp_n & 1) * 64;   // col base within B half
  const int l15 = lane & 15;
  const int l4 = lane >> 4;
  const int l7 = lane & 7;
  const int wdof = wave * 512;         // wave's gload_lds dest slot (u16)

  // T1: XCD-aware 2D swizzle (bid%8 -> XCD; XCD owns 4x8 tile region)
  const int bid = blockIdx.x;
  const int c8 = bid & 7;
  const int j = bid >> 3;
  const int tx = ((c8 & 3) << 2) + (j & 3);    // 0..15
  const int ty = ((c8 >> 2) << 3) + (j >> 2);  // 0..15
  const int brow = ty * BM;
  const int bcol = tx * BN;

  // per-thread swizzled 16B-chunk offsets (u16 elems) for k-slice 0/1
  const int cko0 = ((l4 ^ l7) << 3);
  const int cko1 = (((4 + l4) ^ l7) << 3);

  // LDS read base pointers per (buffer, ks); frag offsets are const imm
  const u16* ARB[2][2];
  const u16* BRB[2][2];
#pragma unroll
  for (int c = 0; c < 2; ++c) {
    ARB[c][0] = sm + LDSOFF(c, 0, warp_m) + l15 * 64 + cko0;
    ARB[c][1] = sm + LDSOFF(c, 0, warp_m) + l15 * 64 + cko1;
    BRB[c][0] = sm + LDSOFF(c, 1, wn2) + bn0 * 64 + l15 * 64 + cko0;
    BRB[c][1] = sm + LDSOFF(c, 1, wn2) + bn0 * 64 + l15 * 64 + cko1;
  }

  // running global staging pointers (pre-swizzled source, rule #21)
  const u16* gp[8];
#pragma unroll
  for (int it = 0; it < 2; ++it) {
    const int chunk = it * 512 + t;
    const int r = chunk >> 3;
    const int sw = ((chunk & 7) ^ (r & 7)) << 3;
    gp[0 + it] = A  + (size_t)(brow + r) * KD + sw;        // A half0
    gp[2 + it] = A  + (size_t)(brow + 128 + r) * KD + sw;  // A half1
    gp[4 + it] = Bw + (size_t)(bcol + r) * KD + sw;        // B half0
    gp[6 + it] = Bw + (size_t)(bcol + 128 + r) * KD + sw;  // B half1
  }

  f32x4 acc[8][4] = {};   // per-wave 128x64 output (AGPR)
  bf16x8 afP[4], afQ[4], bfP[4], bfQ[4];

  // prologue: tile 0 -> buf 0; pre-read c1's A operand
  STAGE_TILE(0)
  asm volatile("s_waitcnt vmcnt(0)" ::: "memory");
  __builtin_amdgcn_s_barrier();
  READ_A4(afP, 0, 0, 0)
  SBAR0;

  for (int kt2 = 0; kt2 < NKT / 2 - 1; ++kt2) {   // tiles 0..61
    TILE(0, 1, 0)
    TILE(1, 1, 0)
  }
  TILE(0, 1, 0)    // tile 62 (stages tile 63 into buf1)
  TILE(1, 0, 1)    // tile 63

  // ---- epilogue: row-max of (acc + bias); gelu deferred to rowmax.
  // C/D layout per 16x16 frag: col = l15, row = l4*4 + j
  float rmax_[8][4];
#pragma unroll
  for (int m = 0; m < 8; ++m)
#pragma unroll
    for (int j2 = 0; j2 < 4; ++j2) rmax_[m][j2] = -1e30f;

#pragma unroll
  for (int n = 0; n < 4; ++n) {
    const float bv = bias[bcol + warp_n * 64 + n * 16 + l15];
#pragma unroll
    for (int m = 0; m < 8; ++m) {
#pragma unroll
      for (int j2 = 0; j2 < 4; ++j2)
        rmax_[m][j2] = fmaxf(rmax_[m][j2], acc[m][n][j2] + bv);
    }
  }

#pragma unroll
  for (int m = 0; m < 8; ++m) {
#pragma unroll
    for (int j2 = 0; j2 < 4; ++j2) {
      float v = rmax_[m][j2];
      v = fmaxf(v, __shfl_xor(v, 1, 64));
      v = fmaxf(v, __shfl_xor(v, 2, 64));
      v = fmaxf(v, __shfl_xor(v, 4, 64));
      v = fmaxf(v, __shfl_xor(v, 8, 64));
      if (l15 == 0) pmx[wave][m * 16 + l4 * 4 + j2] = v;
    }
  }
  __syncthreads();

  if (t < 256) {
    int gm = t >> 7;
    int r = t & 127;
    float v = fmaxf(fmaxf(pmx[gm * 4 + 0][r], pmx[gm * 4 + 1][r]),
                    fmaxf(pmx[gm * 4 + 2][r], pmx[gm * 4 + 3][r]));
    partials[(size_t)tx * MDIM + brow + t] = v;
  }
}

__global__ void rowmax_kernel(const float* __restrict__ partials,
                              float* __restrict__ out) {
  int r = blockIdx.x * blockDim.x + threadIdx.x;
  if (r < MDIM) {
    float m = -1e30f;
#pragma unroll
    for (int tt = 0; tt < NTN; ++tt) m = fmaxf(m, partials[(size_t)tt * MDIM + r]);
    // 2*gelu_tanh(m); valid since row-max >= 0 and gelu is increasing there
    float u = 0.7978845608f * m * (1.0f + 0.044715f * m * m);
    float e = exp2f(u * 2.8853900817779268f);   // 2*log2(e)
    float rc = __builtin_amdgcn_rcpf(e + 1.0f);
    out[r] = 2.0f * m * (1.0f - rc);
  }
}

extern "C" void kernel_launch(void* const* d_in, const int* in_sizes, int n_in,
                              void* d_out, int out_size, void* d_ws, size_t ws_size,
                              hipStream_t stream) {
  const float* x = (const float*)d_in[0];
  const float* w = (const float*)d_in[1];
  const float* bias = (const float*)d_in[2];
  float* out = (float*)d_out;

  u16* xb = (u16*)d_ws;
  u16* wb = xb + (size_t)MDIM * KD;
  float* partials = (float*)(wb + (size_t)NDIM * KD);

  const int n8 = (MDIM * KD) / 8;
  f32_to_bf16_kernel<<<2048, 256, 0, stream>>>(x, w, xb, wb, n8);

  gemm_gelu_max_kernel<<<dim3(256), 512, 0, stream>>>(xb, wb, bias, partials);

  rowmax_kernel<<<MDIM / 256, 256, 0, stream>>>(partials, out);
}